// Round 21
// baseline (46.827 us; speedup 1.0000x reference)
//
#include <hip/hip_runtime.h>
#include <hip/hip_bf16.h>

namespace {

constexpr int Bsz = 64, Cch = 3, Himg = 224, Wimg = 224, Ppat = 16;
constexpr int Dm = 768, NPW = 14, NPATCH = 196, SEQn = 197;
constexpr int Mtot = Bsz * NPATCH;   // 12544
constexpr int Ktot = 768, Ntot = 768;
constexpr int BM = 64, BN = 256, BK = 64;
constexpr int MT = Mtot / BM;        // 196
constexpr int NT2 = Ntot / BN;       // 3
constexpr int KT = Ktot / BK;        // 12
constexpr int NBLK = MT * NT2;       // 588
constexpr int TA = BM * BK;          // 4096 elems = 8 KB
constexpr int TB = 128 * BK;         // 8192 elems = 16 KB (one 128-row slab)
constexpr size_t WT_ELEMS = (size_t)(Ntot / 128) * KT * TB;  // 589,824
constexpr int WPREP_BLK = (Ktot / 8) * Ntot / 256;         // 288
constexpr int CLS_BLK = Bsz * Dm / 256;                    // 192

typedef __attribute__((ext_vector_type(8))) short bf16x8;
typedef __attribute__((ext_vector_type(4))) float f32x4;

__device__ inline unsigned short f2bf(float f) {
  __bf16 h = (__bf16)f;  // RNE; clang fuses pairs into v_cvt_pk_bf16_f32
  union { __bf16 h; unsigned short u; } c;
  c.h = h;
  return c.u;
}

union Pack8 { unsigned short s[8]; uint4 v; };

// ---------------- prepass: W -> Wt (swizzled bf16 tiles), cls row -----------
// Wt slab (nb,kt) [128x64]: elem (n',k') at (nb*KT+kt)*TB + ((n'*BK+k')^((n'&7)<<3))
// Pre-swizzled so LINEAR global_load_lds staging yields the swizzled LDS
// image the ds_read_b128 fragment reads expect (m173 pattern).
__global__ void prep_kernel(const float* __restrict__ W,
                            const float* __restrict__ pos, const float* __restrict__ cls,
                            unsigned short* __restrict__ Wt, float* __restrict__ out) {
  const int bid = blockIdx.x;
  const int t = threadIdx.x;
  if (bid < WPREP_BLK) {  // ---- W prep (swizzled slabs)
    int cid = bid * 256 + t;
    int kc = cid / Ntot;                      // k-chunk of 8 (0..95)
    int n = cid - kc * Ntot;
    int nb = n >> 7;                          // 0..5
    int np = n & 127;
    int kt = kc >> 3;
    int k8 = (kc & 7) * 8;
    Pack8 p;
#pragma unroll
    for (int j = 0; j < 8; ++j) p.s[j] = f2bf(W[(size_t)(kc * 8 + j) * Ntot + n]);
    int sidx = (np * BK + k8) ^ ((np & 7) << 3);
    *reinterpret_cast<uint4*>(Wt + (size_t)(nb * KT + kt) * TB + sidx) = p.v;
  } else {  // ---- class-token row (s = 0)
    int i = (bid - WPREP_BLK) * 256 + t;
    int b = i / Dm;
    int d = i - b * Dm;
    out[(size_t)b * (SEQn * Dm) + d] = cls[d] + pos[d];
  }
}

// ---------------- FUSED GEMM: 64x256 block (N-growth), single buffer --------
// R17's fused chain with DOUBLED per-step compute: BN 128->256 doubles MFMA
// per step (the serial x-gather chain is unchanged — B-DMA is async issue
// only) and halves block-steps/CU (588 x 12 / 256 = 27.6 vs R17's 55).
// x redundancy drops 6x -> 3x. LDS 8+32 = 40 KB -> 4 blocks/CU, grid 588
// all co-resident. ni-loop chunked into two bfr[4] passes to hold VGPR<=128
// (launch_bounds(256,4)); spill signature = WRITE_SIZE balloon (R19 lesson).
__global__ __launch_bounds__(256, 4)
void gemm_kernel(const float* __restrict__ x, const unsigned short* __restrict__ Wt,
                 const float* __restrict__ bias, const float* __restrict__ pos,
                 float* __restrict__ out) {
  __shared__ unsigned short A[TA];       // 8 KB
  __shared__ unsigned short B[2][TB];    // 32 KB (two 128-row slabs)

  // m204 bijective XCD swizzle (NBLK=588 = 8*73+4); bn fastest within a
  // chunk -> this bm's x panel re-read 3x back-to-back in one XCD's L2.
  const int orig = blockIdx.x;
  const int xcd = orig & 7;
  constexpr int Q = NBLK >> 3, R = NBLK & 7;  // 73, 4
  const int wg = (xcd < R ? xcd * (Q + 1) : R * (Q + 1) + (xcd - R) * Q) + (orig >> 3);
  const int bm = wg / NT2;
  const int bn = wg - bm * NT2;

  const int t = threadIdx.x;
  const int lane = t & 63;
  const int wid = t >> 6;              // 4 waves: 2 (M) x 2 (N), each 32x128
  const int wr = wid >> 1, wc = wid & 1;
  const int fr = lane & 15, fq = lane >> 4;

  // A staging geometry: thread covers float4 k-group c4, rows r0 + 16*i
  const int c4 = t & 15;
  const int r0 = t >> 4;
  int a_base[4];
#pragma unroll
  for (int i = 0; i < 4; ++i) {
    int m = bm * BM + r0 + 16 * i;
    int b = m / NPATCH;
    int pidx = m - b * NPATCH;
    int ph = pidx / NPW;
    int pw = pidx - ph * NPW;
    a_base[i] = ((b * Cch) * Himg + ph * Ppat) * Wimg + pw * Ppat;
  }
  // two B slabs per block: nb = 2*bn, 2*bn+1
  const unsigned short* bSrc0 = Wt + (size_t)((2 * bn) * KT) * TB + t * 8;
  const unsigned short* bSrc1 = Wt + (size_t)((2 * bn + 1) * KT) * TB + t * 8;

  f32x4 acc[2][8];
#pragma unroll
  for (int mi = 0; mi < 2; ++mi)
#pragma unroll
    for (int ni = 0; ni < 8; ++ni) acc[mi][ni] = {0.f, 0.f, 0.f, 0.f};

  for (int kt = 0; kt < KT; ++kt) {
    // ---- stage phase: x loads + 8 B-DMA in flight together, then cvt+write
    float4 av[4];
    {
      int kg = kt * BK + c4 * 4;
      int c = kg >> 8, pi = (kg >> 4) & 15, pj = kg & 15;
      int off = (c * Himg + pi) * Wimg + pj;
#pragma unroll
      for (int i = 0; i < 4; ++i)
        av[i] = *reinterpret_cast<const float4*>(x + a_base[i] + off);
    }
#pragma unroll
    for (int i = 0; i < 4; ++i)
      __builtin_amdgcn_global_load_lds(
          (const __attribute__((address_space(1))) unsigned int*)(bSrc0 + kt * TB + i * 2048),
          (__attribute__((address_space(3))) unsigned int*)(&B[0][t * 8 + i * 2048]),
          16, 0, 0);
#pragma unroll
    for (int i = 0; i < 4; ++i)
      __builtin_amdgcn_global_load_lds(
          (const __attribute__((address_space(1))) unsigned int*)(bSrc1 + kt * TB + i * 2048),
          (__attribute__((address_space(3))) unsigned int*)(&B[1][t * 8 + i * 2048]),
          16, 0, 0);
#pragma unroll
    for (int i = 0; i < 4; ++i) {
      int row = r0 + 16 * i;
      int idx = (row * BK + c4 * 4) ^ ((row & 7) << 3);
      ushort4 pk = make_ushort4(f2bf(av[i].x), f2bf(av[i].y), f2bf(av[i].z), f2bf(av[i].w));
      *reinterpret_cast<ushort4*>(&A[idx]) = pk;
    }
    __syncthreads();                   // drains DMA (vmcnt) + ds_writes (lgkm)
    // ---- compute phase: wave tile 32x128, 16 MFMA/step (ni chunked 2x4)
#pragma unroll
    for (int ks = 0; ks < 2; ++ks) {
      bf16x8 af[2];
#pragma unroll
      for (int mi = 0; mi < 2; ++mi) {
        int row = wr * 32 + mi * 16 + fr;
        int idx = (row * BK + ks * 32 + fq * 8) ^ ((row & 7) << 3);
        af[mi] = *reinterpret_cast<const bf16x8*>(&A[idx]);
      }
#pragma unroll
      for (int nh = 0; nh < 2; ++nh) {
        bf16x8 bfr[4];
#pragma unroll
        for (int ni = 0; ni < 4; ++ni) {
          int n = wc * 128 + (nh * 4 + ni) * 16 + fr;   // 0..255
          int half = n >> 7;
          int np = n & 127;
          int idx = (np * BK + ks * 32 + fq * 8) ^ ((np & 7) << 3);
          bfr[ni] = *reinterpret_cast<const bf16x8*>(&B[half][idx]);
        }
#pragma unroll
        for (int mi = 0; mi < 2; ++mi)
#pragma unroll
          for (int ni = 0; ni < 4; ++ni)
            acc[mi][nh * 4 + ni] = __builtin_amdgcn_mfma_f32_16x16x32_bf16(
                af[mi], bfr[ni], acc[mi][nh * 4 + ni], 0, 0, 0);
      }
    }
    if (kt + 1 < KT) __syncthreads();  // all reads done before next overwrite
  }

  // ---- epilogue: per (mi,j) the 8 ni-stores are adjacent, covering 512B
  // contiguous per row (superset of the proven 256B granule pattern).
  const int n0 = bn * BN + wc * 128;
  float bv[8];
#pragma unroll
  for (int ni = 0; ni < 8; ++ni) bv[ni] = bias[n0 + ni * 16 + fr];
#pragma unroll
  for (int mi = 0; mi < 2; ++mi) {
#pragma unroll
    for (int j = 0; j < 4; ++j) {
      int m = bm * BM + wr * 32 + mi * 16 + fq * 4 + j;
      int b = m / NPATCH;
      int s = m - b * NPATCH + 1;  // +1: class token at s=0
      float* orow = out + ((size_t)b * SEQn + s) * Dm + n0;
      const float* prow = pos + (size_t)s * Dm + n0;
#pragma unroll
      for (int ni = 0; ni < 8; ++ni) {
        int d = ni * 16 + fr;
        orow[d] = acc[mi][ni][j] + bv[ni] + prow[d];
      }
    }
  }
}

}  // namespace

extern "C" void kernel_launch(void* const* d_in, const int* in_sizes, int n_in,
                              void* d_out, int out_size, void* d_ws, size_t ws_size,
                              hipStream_t stream) {
  const float* x = (const float*)d_in[0];
  const float* W = (const float*)d_in[1];
  const float* bias = (const float*)d_in[2];
  const float* pos = (const float*)d_in[3];
  const float* cls = (const float*)d_in[4];
  float* out = (float*)d_out;
  unsigned short* Wt = (unsigned short*)d_ws;  // needs 1.18 MB

  prep_kernel<<<WPREP_BLK + CLS_BLK, 256, 0, stream>>>(W, pos, cls, Wt, out);
  gemm_kernel<<<NBLK, 256, 0, stream>>>(x, Wt, bias, pos, out);
}

// Round 22
// 38.557 us; speedup vs baseline: 1.2145x; 1.2145x over previous
//
#include <hip/hip_runtime.h>
#include <hip/hip_bf16.h>

namespace {

constexpr int Bsz = 64, Cch = 3, Himg = 224, Wimg = 224, Ppat = 16;
constexpr int Dm = 768, NPW = 14, NPATCH = 196, SEQn = 197;
constexpr int Mtot = Bsz * NPATCH;   // 12544
constexpr int Ktot = 768, Ntot = 768;
constexpr int BM = 64, BN = 128, BK = 64;
constexpr int MT = Mtot / BM;        // 196
constexpr int NT = Ntot / BN;        // 6
constexpr int KT = Ktot / BK;        // 12
constexpr int NBLK = MT * NT;        // 1176 (divisible by 8)
constexpr int TA = BM * BK;          // 4096 elems = 8 KB
constexpr int TB = BN * BK;          // 8192 elems = 16 KB
constexpr size_t WT_ELEMS = (size_t)NT * KT * TB;          // 589,824
constexpr int WPREP_BLK = (Ktot / 8) * Ntot / 256;         // 288
constexpr int CLS_BLK = Bsz * Dm / 256;                    // 192

typedef __attribute__((ext_vector_type(8))) short bf16x8;
typedef __attribute__((ext_vector_type(4))) float f32x4;

__device__ inline unsigned short f2bf(float f) {
  __bf16 h = (__bf16)f;  // RNE; clang fuses pairs into v_cvt_pk_bf16_f32
  union { __bf16 h; unsigned short u; } c;
  c.h = h;
  return c.u;
}

union Pack8 { unsigned short s[8]; uint4 v; };

// ---------------- prepass: W -> Wt (swizzled bf16 tiles), cls row -----------
// Wt tile (nb,kt) [128x64]: elem (n',k') at (nb*KT+kt)*TB + ((n'*BK+k')^((n'&7)<<3))
// Pre-swizzled so LINEAR global_load_lds staging yields the swizzled LDS
// image the ds_read_b128 fragment reads expect (m173 pattern).
__global__ void prep_kernel(const float* __restrict__ W,
                            const float* __restrict__ pos, const float* __restrict__ cls,
                            unsigned short* __restrict__ Wt, float* __restrict__ out) {
  const int bid = blockIdx.x;
  const int t = threadIdx.x;
  if (bid < WPREP_BLK) {  // ---- W prep (swizzled tiles)
    int cid = bid * 256 + t;
    int kc = cid / Ntot;                      // k-chunk of 8 (0..95)
    int n = cid - kc * Ntot;
    int nb = n >> 7;                          // 0..5
    int np = n & 127;
    int kt = kc >> 3;
    int k8 = (kc & 7) * 8;
    Pack8 p;
#pragma unroll
    for (int j = 0; j < 8; ++j) p.s[j] = f2bf(W[(size_t)(kc * 8 + j) * Ntot + n]);
    int sidx = (np * BK + k8) ^ ((np & 7) << 3);
    *reinterpret_cast<uint4*>(Wt + (size_t)(nb * KT + kt) * TB + sidx) = p.v;
  } else {  // ---- class-token row (s = 0)
    int i = (bid - WPREP_BLK) * 256 + t;
    int b = i / Dm;
    int d = i - b * Dm;
    out[(size_t)b * (SEQn * Dm) + d] = cls[d] + pos[d];
  }
}

// ---------------- FUSED GEMM: in-kernel A staging, single buffer ------------
// R17/R20 base (measured best, reproduced 38.81/38.68us): 4 waves 2x2 of
// 32x64, 24 KB LDS, grid 1176 all co-resident (~4.6 blocks/CU = measured
// optimum of the co-residency curve from BOTH sides: 2.3/CU -> 47-52us,
// 4.6/CU -> 38.7us, 8/CU -> 44us). launch_bounds STAYS (256,5) — R19 proved
// (256,6) squeezes VGPR 48->40 and spills staging temps (WRITE +12 MB).
// Added this round (single change): T5 s_setprio around the MFMA cluster —
// scalar hint, zero reg-pressure; in this ~4.6-independent-desynced-blocks
// regime (m191's), compute-phase waves win issue arbitration vs staging.
__global__ __launch_bounds__(256, 5)
void gemm_kernel(const float* __restrict__ x, const unsigned short* __restrict__ Wt,
                 const float* __restrict__ bias, const float* __restrict__ pos,
                 float* __restrict__ out) {
  __shared__ unsigned short A[TA];     // 8 KB
  __shared__ unsigned short B[TB];     // 16 KB

  // XCD-chunked bijective swizzle (NBLK % 8 == 0); bn fastest within a chunk
  // -> this bm's x panel (192 KB fp32) re-read 6x back-to-back in one L2.
  const int orig = blockIdx.x;
  const int wg = (orig & 7) * (NBLK / 8) + (orig >> 3);
  const int bm = wg / NT;
  const int bn = wg - bm * NT;

  const int t = threadIdx.x;
  const int lane = t & 63;
  const int wid = t >> 6;              // 4 waves: 2 (M) x 2 (N), each 32x64
  const int wr = wid >> 1, wc = wid & 1;
  const int fr = lane & 15, fq = lane >> 4;

  // A staging geometry: thread covers float4 k-group c4, rows r0 + 16*i
  const int c4 = t & 15;
  const int r0 = t >> 4;
  int a_base[4];
#pragma unroll
  for (int i = 0; i < 4; ++i) {
    int m = bm * BM + r0 + 16 * i;
    int b = m / NPATCH;
    int pidx = m - b * NPATCH;
    int ph = pidx / NPW;
    int pw = pidx - ph * NPW;
    a_base[i] = ((b * Cch) * Himg + ph * Ppat) * Wimg + pw * Ppat;
  }
  const unsigned short* bSrc = Wt + (size_t)(bn * KT) * TB + t * 8;

  f32x4 acc[2][4];
#pragma unroll
  for (int mi = 0; mi < 2; ++mi)
#pragma unroll
    for (int ni = 0; ni < 4; ++ni) acc[mi][ni] = {0.f, 0.f, 0.f, 0.f};

  for (int kt = 0; kt < KT; ++kt) {
    // ---- stage phase: x loads + B DMA in flight together, then cvt+write
    float4 av[4];
    {
      int kg = kt * BK + c4 * 4;
      int c = kg >> 8, pi = (kg >> 4) & 15, pj = kg & 15;
      int off = (c * Himg + pi) * Wimg + pj;
#pragma unroll
      for (int i = 0; i < 4; ++i)
        av[i] = *reinterpret_cast<const float4*>(x + a_base[i] + off);
    }
#pragma unroll
    for (int i = 0; i < 4; ++i)
      __builtin_amdgcn_global_load_lds(
          (const __attribute__((address_space(1))) unsigned int*)(bSrc + kt * TB + i * 2048),
          (__attribute__((address_space(3))) unsigned int*)(&B[t * 8 + i * 2048]),
          16, 0, 0);
#pragma unroll
    for (int i = 0; i < 4; ++i) {
      int row = r0 + 16 * i;
      int idx = (row * BK + c4 * 4) ^ ((row & 7) << 3);
      ushort4 pk = make_ushort4(f2bf(av[i].x), f2bf(av[i].y), f2bf(av[i].z), f2bf(av[i].w));
      *reinterpret_cast<ushort4*>(&A[idx]) = pk;
    }
    __syncthreads();                   // drains DMA (vmcnt) + ds_writes (lgkm)
    // ---- compute phase (T5: prefer this wave while other blocks stage)
    __builtin_amdgcn_s_setprio(1);
#pragma unroll
    for (int ks = 0; ks < 2; ++ks) {
      bf16x8 af[2], bfr[4];
#pragma unroll
      for (int mi = 0; mi < 2; ++mi) {
        int row = wr * 32 + mi * 16 + fr;
        int idx = (row * BK + ks * 32 + fq * 8) ^ ((row & 7) << 3);
        af[mi] = *reinterpret_cast<const bf16x8*>(&A[idx]);
      }
#pragma unroll
      for (int ni = 0; ni < 4; ++ni) {
        int n = wc * 64 + ni * 16 + fr;
        int idx = (n * BK + ks * 32 + fq * 8) ^ ((n & 7) << 3);
        bfr[ni] = *reinterpret_cast<const bf16x8*>(&B[idx]);
      }
#pragma unroll
      for (int mi = 0; mi < 2; ++mi)
#pragma unroll
        for (int ni = 0; ni < 4; ++ni)
          acc[mi][ni] = __builtin_amdgcn_mfma_f32_16x16x32_bf16(
              af[mi], bfr[ni], acc[mi][ni], 0, 0, 0);
    }
    __builtin_amdgcn_s_setprio(0);
    if (kt + 1 < KT) __syncthreads();  // all reads done before next overwrite
  }

  // ---- epilogue: R5/R10 pattern (measured WRITE_SIZE == ideal 37.6 MB):
  // per (mi,j) the 4 ni-stores are adjacent, covering 256B contiguous per row.
  const int n0 = bn * BN + wc * 64;
  float bv[4];
#pragma unroll
  for (int ni = 0; ni < 4; ++ni) bv[ni] = bias[n0 + ni * 16 + fr];
#pragma unroll
  for (int mi = 0; mi < 2; ++mi) {
#pragma unroll
    for (int j = 0; j < 4; ++j) {
      int m = bm * BM + wr * 32 + mi * 16 + fq * 4 + j;
      int b = m / NPATCH;
      int s = m - b * NPATCH + 1;  // +1: class token at s=0
      float* orow = out + ((size_t)b * SEQn + s) * Dm + n0;
      const float* prow = pos + (size_t)s * Dm + n0;
#pragma unroll
      for (int ni = 0; ni < 4; ++ni) {
        int d = ni * 16 + fr;
        orow[d] = acc[mi][ni][j] + bv[ni] + prow[d];
      }
    }
  }
}

}  // namespace

extern "C" void kernel_launch(void* const* d_in, const int* in_sizes, int n_in,
                              void* d_out, int out_size, void* d_ws, size_t ws_size,
                              hipStream_t stream) {
  const float* x = (const float*)d_in[0];
  const float* W = (const float*)d_in[1];
  const float* bias = (const float*)d_in[2];
  const float* pos = (const float*)d_in[3];
  const float* cls = (const float*)d_in[4];
  float* out = (float*)d_out;
  unsigned short* Wt = (unsigned short*)d_ws;  // needs 1.18 MB

  prep_kernel<<<WPREP_BLK + CLS_BLK, 256, 0, stream>>>(W, pos, cls, Wt, out);
  gemm_kernel<<<NBLK, 256, 0, stream>>>(x, Wt, bias, pos, out);
}